// Round 2
// baseline (259.495 us; speedup 1.0000x reference)
//
#include <hip/hip_runtime.h>
#include <math.h>

#define BB 64
#define TT 577
#define DD 768
#define DENS 519   // int(577*0.9)
#define NSKIP 58

// Order-preserving map: double bits -> u64 (lexicographic == numeric order).
__device__ inline unsigned long long key_of(double z) {
    long long b = __double_as_longlong(z);
    return (b < 0) ? ~(unsigned long long)b
                   : ((unsigned long long)b | 0x8000000000000000ULL);
}
__device__ inline double key_inv(unsigned long long k) {
    long long b = (k >> 63) ? (long long)(k & 0x7fffffffffffffffULL)
                            : ~(long long)k;
    return __longlong_as_double(b);
}

// ---------------------------------------------------------------------------
// Kernel 1: z[b,t] = dot(x[b,t,:], w) + bias (fp64 accumulate), stored as an
// order-preserving u64 key. NO sigmoid here (monotone -> same ranking).
// One wave per row; float4 coalesced loads. Memory-bound.
// ---------------------------------------------------------------------------
__global__ __launch_bounds__(256) void k_prob(const float* __restrict__ x,
                                              const float* __restrict__ w,
                                              const float* __restrict__ bias,
                                              unsigned long long* __restrict__ keys,
                                              int nrows) {
    int wave = (int)((blockIdx.x * blockDim.x + threadIdx.x) >> 6);
    int lane = threadIdx.x & 63;
    if (wave >= nrows) return;
    const float4* r4 = (const float4*)(x + (size_t)wave * DD);
    const float4* w4 = (const float4*)w;
    double acc = 0.0;
#pragma unroll
    for (int i = 0; i < 3; ++i) {
        float4 a = r4[lane + 64 * i];
        float4 b = w4[lane + 64 * i];
        acc += (double)a.x * (double)b.x + (double)a.y * (double)b.y
             + (double)a.z * (double)b.z + (double)a.w * (double)b.w;
    }
#pragma unroll
    for (int off = 32; off; off >>= 1)
        acc += __shfl_down(acc, off, 64);
    if (lane == 0) {
        keys[wave] = key_of(acc + (double)bias[0]);
    }
}

// ---------------------------------------------------------------------------
// Kernel 2: per-batch stable ranking via u64 key compares + softmax weights.
// r_desc(i) = #{j: k[j]>k[i]} + #{j<i: k[j]==k[i]}  (jax top_k order, desc)
// r_asc(i)  = #{j: k[j]<k[i]} + #{j<i: k[j]==k[i]}  (jax top_k of -p order)
// Sigmoid evaluated only for the 58 skipped values (softmax stage).
// ---------------------------------------------------------------------------
__global__ __launch_bounds__(640) void k_rank(const unsigned long long* __restrict__ keys,
                                              int* __restrict__ tok_src,
                                              int* __restrict__ skip_src,
                                              float* __restrict__ skip_w) {
    __shared__ unsigned long long p[TT];
    __shared__ unsigned long long sk[NSKIP];
    int b = blockIdx.x;
    int i = threadIdx.x;
    if (i < TT) p[i] = keys[b * TT + i];
    __syncthreads();
    if (i < TT) {
        unsigned long long ki = p[i];
        int r_desc = 0, r_asc = 0;
#pragma unroll 4
        for (int j = 0; j < TT; ++j) {
            unsigned long long kj = p[j];
            bool tie = (kj == ki) & (j < i);
            r_desc += ((kj > ki) | tie) ? 1 : 0;
            r_asc  += ((kj < ki) | tie) ? 1 : 0;
        }
        if (r_desc < DENS)  tok_src[b * DENS + r_desc] = i;
        if (r_asc < NSKIP) { skip_src[b * NSKIP + r_asc] = i; sk[r_asc] = ki; }
    }
    __syncthreads();
    // softmax over sigmoid(z) of the 58 skipped rows — first wave only
    if (i < 64) {
        double pv = -1.0e300;
        if (i < NSKIP) {
            double z = key_inv(sk[i]);
            pv = 1.0 / (1.0 + exp(-z));
        }
        double m = pv;
#pragma unroll
        for (int off = 32; off; off >>= 1) {
            double o = __shfl_down(m, off, 64);
            m = (o > m) ? o : m;
        }
        m = __shfl(m, 0, 64);
        double e = (i < NSKIP) ? exp(pv - m) : 0.0;
        double s = e;
#pragma unroll
        for (int off = 32; off; off >>= 1)
            s += __shfl_down(s, off, 64);
        s = __shfl(s, 0, 64);
        if (i < NSKIP) skip_w[b * NSKIP + i] = (float)(e / s);
    }
}

// ---------------------------------------------------------------------------
// Kernel 3: gather rows. One wave per output row (tokens then skip_tokens).
// ---------------------------------------------------------------------------
__global__ __launch_bounds__(256) void k_gather(const float* __restrict__ x,
                                                const int* __restrict__ tok_src,
                                                const int* __restrict__ skip_src,
                                                float* __restrict__ out) {
    int wave = (int)((blockIdx.x * blockDim.x + threadIdx.x) >> 6);
    int lane = threadIdx.x & 63;
    if (wave >= BB * TT) return;
    int b = wave / TT;
    int k = wave - b * TT;
    int src;
    size_t dst;
    if (k < DENS) {
        src = tok_src[b * DENS + k];
        dst = (size_t)(b * DENS + k) * DD;
    } else {
        int k2 = k - DENS;
        src = skip_src[b * NSKIP + k2];
        dst = (size_t)BB * DENS * DD + (size_t)(b * NSKIP + k2) * DD;
    }
    const float4* s4 = (const float4*)(x + ((size_t)b * TT + src) * DD);
    float4* d4 = (float4*)(out + dst);
#pragma unroll
    for (int i = 0; i < 3; ++i)
        d4[lane + 64 * i] = s4[lane + 64 * i];
}

// ---------------------------------------------------------------------------
// Kernel 4: summary[b,d] = sum_k w[b,k] * skip_tokens[b,k,d]
// One block per batch; 256 threads × 3 columns each.
// ---------------------------------------------------------------------------
__global__ __launch_bounds__(256) void k_summary(const float* __restrict__ skip_tok,
                                                 const float* __restrict__ skip_w,
                                                 float* __restrict__ summary) {
    int b = blockIdx.x;
    int t = threadIdx.x;
    float a0 = 0.f, a1 = 0.f, a2 = 0.f;
    for (int k = 0; k < NSKIP; ++k) {
        float wk = skip_w[b * NSKIP + k];
        const float* row = skip_tok + (size_t)(b * NSKIP + k) * DD;
        a0 += wk * row[t];
        a1 += wk * row[t + 256];
        a2 += wk * row[t + 512];
    }
    summary[b * DD + t]       = a0;
    summary[b * DD + t + 256] = a1;
    summary[b * DD + t + 512] = a2;
}

extern "C" void kernel_launch(void* const* d_in, const int* in_sizes, int n_in,
                              void* d_out, int out_size, void* d_ws, size_t ws_size,
                              hipStream_t stream) {
    const float* x    = (const float*)d_in[0];
    const float* w    = (const float*)d_in[1];
    const float* bias = (const float*)d_in[2];
    float* out = (float*)d_out;
    char* ws = (char*)d_ws;

    const int nrows = BB * TT;                   // 36928
    unsigned long long* keys = (unsigned long long*)ws;              // 36928*8 = 295424 B
    int* tok_src   = (int*)(ws + 295424);                            // 64*519*4 = 132864 B
    int* skip_src  = (int*)(ws + 295424 + 132864);                   // 64*58*4  = 14848 B
    float* skip_w  = (float*)(ws + 295424 + 132864 + 14848);         // 64*58*4  = 14848 B

    k_prob<<<nrows / 4, 256, 0, stream>>>(x, w, bias, keys, nrows);
    k_rank<<<BB, 640, 0, stream>>>(keys, tok_src, skip_src, skip_w);
    k_gather<<<nrows / 4, 256, 0, stream>>>(x, tok_src, skip_src, out);

    float* skip_tok = out + (size_t)BB * DENS * DD;
    float* summary  = out + (size_t)BB * (DENS + NSKIP) * DD;
    k_summary<<<BB, 256, 0, stream>>>(skip_tok, skip_w, summary);
}

// Round 4
// 241.062 us; speedup vs baseline: 1.0765x; 1.0765x over previous
//
#include <hip/hip_runtime.h>
#include <math.h>

#define BB 64
#define TT 577
#define DD 768
#define DENS 519   // int(577*0.9)
#define NSKIP 58
#define NROWS (BB * TT)

typedef float vf4 __attribute__((ext_vector_type(4)));  // clang vector: ok for nontemporal builtin

// Order-preserving map: double bits -> u64 (lexicographic == numeric order).
__device__ inline unsigned long long key_of(double z) {
    long long b = __double_as_longlong(z);
    return (b < 0) ? ~(unsigned long long)b
                   : ((unsigned long long)b | 0x8000000000000000ULL);
}
__device__ inline double key_inv(unsigned long long k) {
    long long b = (k >> 63) ? (long long)(k & 0x7fffffffffffffffULL)
                            : ~(long long)k;
    return __longlong_as_double(b);
}

// ---------------------------------------------------------------------------
// Kernel 1: z[b,t] = dot(x[b,t,:], w) + bias (fp64 accumulate), stored as an
// order-preserving u64 key (no sigmoid: monotone -> same ranking).
// One wave per row; float4 coalesced loads. HBM-bound (~113 MB read).
// ---------------------------------------------------------------------------
__global__ __launch_bounds__(256) void k_prob(const float* __restrict__ x,
                                              const float* __restrict__ w,
                                              const float* __restrict__ bias,
                                              unsigned long long* __restrict__ keys) {
    int wave = (int)((blockIdx.x * blockDim.x + threadIdx.x) >> 6);
    int lane = threadIdx.x & 63;
    if (wave >= NROWS) return;
    const float4* r4 = (const float4*)(x + (size_t)wave * DD);
    const float4* w4 = (const float4*)w;
    double acc = 0.0;
#pragma unroll
    for (int i = 0; i < 3; ++i) {
        float4 a = r4[lane + 64 * i];
        float4 b = w4[lane + 64 * i];
        acc += (double)a.x * (double)b.x + (double)a.y * (double)b.y
             + (double)a.z * (double)b.z + (double)a.w * (double)b.w;
    }
#pragma unroll
    for (int off = 32; off; off >>= 1)
        acc += __shfl_down(acc, off, 64);
    if (lane == 0) {
        keys[wave] = key_of(acc + (double)bias[0]);
    }
}

// ---------------------------------------------------------------------------
// Kernel 2: counting-rank, ONE WAVE PER ROW (full-chip occupancy).
// rank_desc(i) = #{j: k[j]>k[i]} + #{j<i: k[j]==k[i]}  (jax top_k desc order)
// rank_asc(i)  = #{j: k[j]<k[i]} + #{j<i: k[j]==k[i]}  (top_k of -p order)
// Each lane scans 10 j's (coalesced u64, L1-resident per batch); both counters
// packed in one u64 for a single shuffle-reduce.
// ---------------------------------------------------------------------------
__global__ __launch_bounds__(256) void k_rank(const unsigned long long* __restrict__ keys,
                                              int* __restrict__ tok_src,
                                              int* __restrict__ skip_src,
                                              unsigned long long* __restrict__ skip_key) {
    int wave = (int)((blockIdx.x * blockDim.x + threadIdx.x) >> 6);
    int lane = threadIdx.x & 63;
    if (wave >= NROWS) return;
    int b = wave / TT;
    int i = wave - b * TT;
    const unsigned long long* kb = keys + b * TT;
    unsigned long long ki = kb[i];
    int rd = 0, ra = 0;
#pragma unroll
    for (int c = 0; c < 10; ++c) {
        int j = lane + 64 * c;
        if (j < TT) {
            unsigned long long kj = kb[j];
            bool tie = (kj == ki) & (j < i);
            rd += ((kj > ki) | tie) ? 1 : 0;
            ra += ((kj < ki) | tie) ? 1 : 0;
        }
    }
    unsigned long long pack = ((unsigned long long)(unsigned)rd << 32) | (unsigned)ra;
#pragma unroll
    for (int off = 32; off; off >>= 1)
        pack += __shfl_down(pack, off, 64);
    if (lane == 0) {
        int r_desc = (int)(pack >> 32);
        int r_asc  = (int)(pack & 0xffffffffu);
        if (r_desc < DENS) {
            tok_src[b * DENS + r_desc] = i;
        } else {               // r_desc >= DENS  =>  r_asc = 576 - r_desc < NSKIP
            skip_src[b * NSKIP + r_asc] = i;
            skip_key[b * NSKIP + r_asc] = ki;
        }
    }
}

// ---------------------------------------------------------------------------
// Kernel 3: softmax over sigmoid(z) of the 58 skipped rows (wave 0), then
// summary[b,d] = sum_k w_k * x[b, skip_k, d] read directly from x (L3-hot).
// One block per batch, 768 threads (one per output dim).
// ---------------------------------------------------------------------------
__global__ __launch_bounds__(768) void k_soft(const float* __restrict__ x,
                                              const int* __restrict__ skip_src,
                                              const unsigned long long* __restrict__ skip_key,
                                              float* __restrict__ summary) {
    __shared__ float wsh[NSKIP];
    __shared__ int   ssh[NSKIP];
    int b = blockIdx.x;
    int t = threadIdx.x;
    if (t < NSKIP) ssh[t] = skip_src[b * NSKIP + t];
    if (t < 64) {
        double pv = -1.0e300;
        if (t < NSKIP) {
            double z = key_inv(skip_key[b * NSKIP + t]);
            pv = 1.0 / (1.0 + exp(-z));
        }
        double m = pv;
#pragma unroll
        for (int off = 32; off; off >>= 1) {
            double o = __shfl_down(m, off, 64);
            m = (o > m) ? o : m;
        }
        m = __shfl(m, 0, 64);
        double e = (t < NSKIP) ? exp(pv - m) : 0.0;
        double s = e;
#pragma unroll
        for (int off = 32; off; off >>= 1)
            s += __shfl_down(s, off, 64);
        s = __shfl(s, 0, 64);
        if (t < NSKIP) wsh[t] = (float)(e / s);
    }
    __syncthreads();
    float acc = 0.f;
    const float* xb = x + (size_t)b * TT * DD;
    for (int k = 0; k < NSKIP; ++k)
        acc += wsh[k] * xb[(size_t)ssh[k] * DD + t];
    summary[(size_t)b * DD + t] = acc;
}

// ---------------------------------------------------------------------------
// Kernel 4: gather rows (tokens then skip_tokens). One wave per output row;
// non-temporal stores (output never re-read -> don't pollute L2/L3, keep x hot).
// ---------------------------------------------------------------------------
__global__ __launch_bounds__(256) void k_gather(const float* __restrict__ x,
                                                const int* __restrict__ tok_src,
                                                const int* __restrict__ skip_src,
                                                float* __restrict__ out) {
    int wave = (int)((blockIdx.x * blockDim.x + threadIdx.x) >> 6);
    int lane = threadIdx.x & 63;
    if (wave >= NROWS) return;
    int b = wave / TT;
    int k = wave - b * TT;
    int src;
    size_t dst;
    if (k < DENS) {
        src = tok_src[b * DENS + k];
        dst = (size_t)(b * DENS + k) * DD;
    } else {
        int k2 = k - DENS;
        src = skip_src[b * NSKIP + k2];
        dst = (size_t)BB * DENS * DD + (size_t)(b * NSKIP + k2) * DD;
    }
    const vf4* s4 = (const vf4*)(x + ((size_t)b * TT + src) * DD);
    vf4* d4 = (vf4*)(out + dst);
#pragma unroll
    for (int i = 0; i < 3; ++i) {
        vf4 v = s4[lane + 64 * i];
        __builtin_nontemporal_store(v, &d4[lane + 64 * i]);
    }
}

extern "C" void kernel_launch(void* const* d_in, const int* in_sizes, int n_in,
                              void* d_out, int out_size, void* d_ws, size_t ws_size,
                              hipStream_t stream) {
    const float* x    = (const float*)d_in[0];
    const float* w    = (const float*)d_in[1];
    const float* bias = (const float*)d_in[2];
    float* out = (float*)d_out;
    char* ws = (char*)d_ws;

    unsigned long long* keys = (unsigned long long*)ws;              // 36928*8 = 295424 B
    int* tok_src  = (int*)(ws + 295424);                             // 64*519*4 = 132864 B
    int* skip_src = (int*)(ws + 295424 + 132864);                    // 64*58*4  = 14848 B
    unsigned long long* skip_key =
        (unsigned long long*)(ws + 295424 + 132864 + 14848);         // 64*58*8  = 29696 B

    const int nblk = NROWS / 4;  // 9232 blocks, 4 waves each

    k_prob<<<nblk, 256, 0, stream>>>(x, w, bias, keys);
    k_rank<<<nblk, 256, 0, stream>>>(keys, tok_src, skip_src, skip_key);
    k_soft<<<BB, 768, 0, stream>>>(x, skip_src, skip_key,
                                   out + (size_t)BB * (DENS + NSKIP) * DD);
    k_gather<<<nblk, 256, 0, stream>>>(x, tok_src, skip_src, out);
}

// Round 5
// 223.404 us; speedup vs baseline: 1.1616x; 1.0790x over previous
//
#include <hip/hip_runtime.h>
#include <math.h>

#define BB 64
#define TT 577
#define DD 768
#define DENS 519   // int(577*0.9)
#define NSKIP 58
#define NROWS (BB * TT)

typedef float vf4 __attribute__((ext_vector_type(4)));  // clang vector: ok for nontemporal builtin

// Order-preserving map: double bits -> u64 (lexicographic == numeric order).
__device__ inline unsigned long long key_of(double z) {
    long long b = __double_as_longlong(z);
    return (b < 0) ? ~(unsigned long long)b
                   : ((unsigned long long)b | 0x8000000000000000ULL);
}
__device__ inline double key_inv(unsigned long long k) {
    long long b = (k >> 63) ? (long long)(k & 0x7fffffffffffffffULL)
                            : ~(long long)k;
    return __longlong_as_double(b);
}

// ---------------------------------------------------------------------------
// Kernel 1: z[b,t] = dot(x[b,t,:], w) + bias (fp64 accumulate), stored as an
// order-preserving u64 key (no sigmoid: monotone -> same ranking).
// One wave per row; float4 coalesced loads. HBM-bound (~113 MB read).
// ---------------------------------------------------------------------------
__global__ __launch_bounds__(256) void k_prob(const float* __restrict__ x,
                                              const float* __restrict__ w,
                                              const float* __restrict__ bias,
                                              unsigned long long* __restrict__ keys) {
    int wave = (int)((blockIdx.x * blockDim.x + threadIdx.x) >> 6);
    int lane = threadIdx.x & 63;
    if (wave >= NROWS) return;
    const float4* r4 = (const float4*)(x + (size_t)wave * DD);
    const float4* w4 = (const float4*)w;
    double acc = 0.0;
#pragma unroll
    for (int i = 0; i < 3; ++i) {
        float4 a = r4[lane + 64 * i];
        float4 b = w4[lane + 64 * i];
        acc += (double)a.x * (double)b.x + (double)a.y * (double)b.y
             + (double)a.z * (double)b.z + (double)a.w * (double)b.w;
    }
#pragma unroll
    for (int off = 32; off; off >>= 1)
        acc += __shfl_down(acc, off, 64);
    if (lane == 0) {
        keys[wave] = key_of(acc + (double)bias[0]);
    }
}

// ---------------------------------------------------------------------------
// Kernel 2 (FUSED rank + scatter-copy): one wave per input row.
// rank_desc(i) = #{j: k[j]>k[i]} + #{j<i: k[j]==k[i]}  (jax top_k desc order)
// rank_asc(i)  = #{j: k[j]<k[i]} + #{j<i: k[j]==k[i]}  (top_k of -p order)
// Every row lands in exactly one output slot (tokens if r_desc<DENS, else
// skip_tokens at r_asc) -> scatter: sequential streaming read of x (L3-hot),
// row-coalesced nt write to out. Kills k_gather + tok_src round trip.
// xor-butterfly reduce so ALL lanes hold the rank (needed for the copy dst).
// ---------------------------------------------------------------------------
__global__ __launch_bounds__(256) void k_rankscatter(const float* __restrict__ x,
                                                     const unsigned long long* __restrict__ keys,
                                                     int* __restrict__ skip_src,
                                                     unsigned long long* __restrict__ skip_key,
                                                     float* __restrict__ out) {
    int wave = (int)((blockIdx.x * blockDim.x + threadIdx.x) >> 6);
    int lane = threadIdx.x & 63;
    if (wave >= NROWS) return;
    int b = wave / TT;
    int i = wave - b * TT;
    const unsigned long long* kb = keys + b * TT;
    unsigned long long ki = kb[i];
    int rd = 0, ra = 0;
#pragma unroll
    for (int c = 0; c < 10; ++c) {
        int j = lane + 64 * c;
        if (j < TT) {
            unsigned long long kj = kb[j];
            bool tie = (kj == ki) & (j < i);
            rd += ((kj > ki) | tie) ? 1 : 0;
            ra += ((kj < ki) | tie) ? 1 : 0;
        }
    }
    unsigned long long pack = ((unsigned long long)(unsigned)rd << 32) | (unsigned)ra;
#pragma unroll
    for (int off = 32; off; off >>= 1)
        pack += __shfl_xor(pack, off, 64);      // all lanes get the total
    int r_desc = (int)(pack >> 32);
    int r_asc  = (int)(pack & 0xffffffffu);

    size_t dst;
    if (r_desc < DENS) {
        dst = (size_t)(b * DENS + r_desc) * DD;
    } else {               // r_desc >= DENS  =>  r_asc = 576 - r_desc < NSKIP
        dst = (size_t)BB * DENS * DD + (size_t)(b * NSKIP + r_asc) * DD;
        if (lane == 0) {
            skip_src[b * NSKIP + r_asc] = i;
            skip_key[b * NSKIP + r_asc] = ki;
        }
    }
    const vf4* s4 = (const vf4*)(x + ((size_t)b * TT + i) * DD);
    vf4* d4 = (vf4*)(out + dst);
#pragma unroll
    for (int c = 0; c < 3; ++c) {
        vf4 v = s4[lane + 64 * c];
        __builtin_nontemporal_store(v, &d4[lane + 64 * c]);
    }
}

// ---------------------------------------------------------------------------
// Kernel 3: softmax over sigmoid(z) of the 58 skipped rows (wave 0), then
// summary[b,d] = sum_k w_k * x[b, skip_k, d] read directly from x (L3-hot).
// One block per batch, 768 threads (one per output dim).
// ---------------------------------------------------------------------------
__global__ __launch_bounds__(768) void k_soft(const float* __restrict__ x,
                                              const int* __restrict__ skip_src,
                                              const unsigned long long* __restrict__ skip_key,
                                              float* __restrict__ summary) {
    __shared__ float wsh[NSKIP];
    __shared__ int   ssh[NSKIP];
    int b = blockIdx.x;
    int t = threadIdx.x;
    if (t < NSKIP) ssh[t] = skip_src[b * NSKIP + t];
    if (t < 64) {
        double pv = -1.0e300;
        if (t < NSKIP) {
            double z = key_inv(skip_key[b * NSKIP + t]);
            pv = 1.0 / (1.0 + exp(-z));
        }
        double m = pv;
#pragma unroll
        for (int off = 32; off; off >>= 1) {
            double o = __shfl_down(m, off, 64);
            m = (o > m) ? o : m;
        }
        m = __shfl(m, 0, 64);
        double e = (t < NSKIP) ? exp(pv - m) : 0.0;
        double s = e;
#pragma unroll
        for (int off = 32; off; off >>= 1)
            s += __shfl_down(s, off, 64);
        s = __shfl(s, 0, 64);
        if (t < NSKIP) wsh[t] = (float)(e / s);
    }
    __syncthreads();
    float acc = 0.f;
    const float* xb = x + (size_t)b * TT * DD;
    for (int k = 0; k < NSKIP; ++k)
        acc += wsh[k] * xb[(size_t)ssh[k] * DD + t];
    summary[(size_t)b * DD + t] = acc;
}

extern "C" void kernel_launch(void* const* d_in, const int* in_sizes, int n_in,
                              void* d_out, int out_size, void* d_ws, size_t ws_size,
                              hipStream_t stream) {
    const float* x    = (const float*)d_in[0];
    const float* w    = (const float*)d_in[1];
    const float* bias = (const float*)d_in[2];
    float* out = (float*)d_out;
    char* ws = (char*)d_ws;

    unsigned long long* keys = (unsigned long long*)ws;              // 36928*8 = 295424 B
    int* skip_src = (int*)(ws + 295424);                             // 64*58*4  = 14848 B
    unsigned long long* skip_key =
        (unsigned long long*)(ws + 295424 + 14848);                  // 64*58*8  = 29696 B

    const int nblk = NROWS / 4;  // 9232 blocks, 4 waves each

    k_prob<<<nblk, 256, 0, stream>>>(x, w, bias, keys);
    k_rankscatter<<<nblk, 256, 0, stream>>>(x, keys, skip_src, skip_key, out);
    k_soft<<<BB, 768, 0, stream>>>(x, skip_src, skip_key,
                                   out + (size_t)BB * (DENS + NSKIP) * DD);
}